// Round 17
// baseline (223.037 us; speedup 1.0000x reference)
//
#include <hip/hip_runtime.h>

#define B_ 4
#define T_ 2048
#define C_ 1024
#define H_ 16
#define D_ 64

typedef _Float16 f16x8 __attribute__((ext_vector_type(8)));
typedef __fp16 fp16x2 __attribute__((ext_vector_type(2)));
typedef float f32x4 __attribute__((ext_vector_type(4)));
typedef unsigned short u16x8 __attribute__((ext_vector_type(8)));

#define MFMA16 __builtin_amdgcn_mfma_f32_16x16x32_f16
#define SCALE2 11.541560327111707f   /* 8 * log2(e), pre-folded into Q */

__device__ __forceinline__ unsigned pk2(float a, float b) {
    fp16x2 p = __builtin_amdgcn_cvt_pkrtz(a, b);
    return __builtin_bit_cast(unsigned, p);
}

__device__ __forceinline__ void gl_lds16(const _Float16* g, unsigned short* lds) {
    __builtin_amdgcn_global_load_lds(
        (const __attribute__((address_space(1))) unsigned int*)g,
        (__attribute__((address_space(3))) unsigned int*)lds, 16, 0, 0);
}

// ---------------------------------------------------------------------------
// convx: x fp32 -> Xf fp16.  grid 4096, block 256.
// ---------------------------------------------------------------------------
__global__ __launch_bounds__(256) void convx_kernel(const float* __restrict__ x,
                                                    _Float16* __restrict__ Xf) {
    size_t i = ((size_t)blockIdx.x * 256 + threadIdx.x) * 8;
    f32x4 a = *reinterpret_cast<const f32x4*>(x + i);
    f32x4 b = *reinterpret_cast<const f32x4*>(x + i + 4);
    f16x8 o;
    o[0] = (_Float16)a[0]; o[1] = (_Float16)a[1]; o[2] = (_Float16)a[2]; o[3] = (_Float16)a[3];
    o[4] = (_Float16)b[0]; o[5] = (_Float16)b[1]; o[6] = (_Float16)b[2]; o[7] = (_Float16)b[3];
    *reinterpret_cast<f16x8*>(Xf + i) = o;
}

// ---------------------------------------------------------------------------
// convw_qkv: W[h][c][d] fp32 -> Wt[h][d][c] fp16 (transposed).  grid(8,16,3).
// ---------------------------------------------------------------------------
__global__ __launch_bounds__(256) void convw_qkv_kernel(
    const float* __restrict__ Wq, const float* __restrict__ Wk, const float* __restrict__ Wv,
    _Float16* __restrict__ Wqt, _Float16* __restrict__ Wkt, _Float16* __restrict__ Wvt)
{
    __shared__ unsigned short Wl[128][72];
    const int ct = blockIdx.x, h = blockIdx.y, m = blockIdx.z;
    const float* src = (m == 0 ? Wq : (m == 1 ? Wk : Wv)) + ((size_t)h * C_ + ct * 128) * D_;
    _Float16* dst = (m == 0 ? Wqt : (m == 1 ? Wkt : Wvt));
    const int tid = threadIdx.x;
    {
        int r = tid >> 1, half = tid & 1;
        #pragma unroll
        for (int i = 0; i < 8; i++) {
            f32x4 v = *reinterpret_cast<const f32x4*>(src + (size_t)r * D_ + half * 32 + i * 4);
            #pragma unroll
            for (int j = 0; j < 4; j++)
                Wl[r][half * 32 + i * 4 + j] = __builtin_bit_cast(unsigned short, (_Float16)v[j]);
        }
    }
    __syncthreads();
    {
        int d = tid >> 2, seg = tid & 3;
        #pragma unroll
        for (int i = 0; i < 4; i++) {
            u16x8 o;
            #pragma unroll
            for (int j = 0; j < 8; j++) o[j] = Wl[seg * 32 + i * 8 + j][d];
            *reinterpret_cast<u16x8*>((unsigned short*)dst + ((size_t)h * D_ + d) * C_ + ct * 128 + seg * 32 + i * 8) = o;
        }
    }
}

// ---------------------------------------------------------------------------
// convw_p: Wp[k][j] fp32 -> Wpt[j][k] fp16.  grid(16,16).
// ---------------------------------------------------------------------------
__global__ __launch_bounds__(256) void convw_p_kernel(const float* __restrict__ Wp,
                                                      _Float16* __restrict__ Wpt)
{
    __shared__ unsigned short Pl[64][72];
    const int jt = blockIdx.x, kt = blockIdx.y;
    const int tid = threadIdx.x;
    {
        int r = tid >> 2, seg = tid & 3;
        #pragma unroll
        for (int i = 0; i < 4; i++) {
            f32x4 v = *reinterpret_cast<const f32x4*>(Wp + (size_t)(kt * 64 + r) * C_ + jt * 64 + seg * 16 + i * 4);
            #pragma unroll
            for (int j = 0; j < 4; j++)
                Pl[r][seg * 16 + i * 4 + j] = __builtin_bit_cast(unsigned short, (_Float16)v[j]);
        }
    }
    __syncthreads();
    {
        int jj = tid >> 2, kseg = tid & 3;
        #pragma unroll
        for (int i = 0; i < 2; i++) {
            u16x8 o;
            #pragma unroll
            for (int j = 0; j < 8; j++) o[j] = Pl[kseg * 16 + i * 8 + j][jj];
            *reinterpret_cast<u16x8*>((unsigned short*)Wpt + (size_t)(jt * 64 + jj) * C_ + kt * 64 + kseg * 16 + i * 8) = o;
        }
    }
}

// ---------------------------------------------------------------------------
// qkv5: X[8192x1024] @ Wcat^T[3072x1024], 128x192 tile, BK=64, 4 waves.
// T3/T4 pipelined: double-buffered LDS (80KB -> 2 blocks/CU), STAGE(t+1)
// issued BEFORE compute(t), counted vmcnt(10) (never 0 in steady state) so
// next-tile DMA stays in flight across raw s_barriers; setprio around MFMA.
// grid(64, 16) = 1024 blocks = 2 uniform generations.
// ---------------------------------------------------------------------------
__global__ __launch_bounds__(256) void qkv5_kernel(
    const _Float16* __restrict__ Xf, const _Float16* __restrict__ Wcat,
    _Float16* __restrict__ Qf, _Float16* __restrict__ Kf, _Float16* __restrict__ Vt)
{
    __shared__ unsigned short As[2][128 * 64];
    __shared__ unsigned short Bs[2][192 * 64];
    const int rt = blockIdx.x, ct = blockIdx.y;
    const int row0 = rt * 128, n0 = ct * 192;
    const int tid = threadIdx.x, wid = tid >> 6, lane = tid & 63;
    const int l15 = lane & 15, g = lane >> 4;
    const int wr = wid >> 1, wc = wid & 1;
    const int lrow = lane >> 3, lcol = (lane & 7) * 8;

    f32x4 acc[4][6];
    #pragma unroll
    for (int mi = 0; mi < 4; mi++)
        #pragma unroll
        for (int ni = 0; ni < 6; ni++) { f32x4 z = {0.f,0.f,0.f,0.f}; acc[mi][ni] = z; }

#define STAGE(BUF, K0)                                                              \
    {                                                                               \
        _Pragma("unroll")                                                           \
        for (int i = 0; i < 4; i++) {                                               \
            int c = wid * 4 + i;                                                    \
            gl_lds16(Xf + (size_t)(row0 + c * 8 + lrow) * C_ + (K0) + lcol,         \
                     &As[BUF][c * 512]);                                            \
        }                                                                           \
        _Pragma("unroll")                                                           \
        for (int i = 0; i < 6; i++) {                                               \
            int c = wid * 6 + i;                                                    \
            gl_lds16(Wcat + (size_t)(n0 + c * 8 + lrow) * C_ + (K0) + lcol,         \
                     &Bs[BUF][c * 512]);                                            \
        }                                                                           \
    }

#define KSTEP(T, BUF)                                                               \
    {                                                                               \
        if ((T) + 1 < 16) {                                                         \
            STAGE((BUF) ^ 1, ((T) + 1) * 64)                                        \
            asm volatile("s_waitcnt vmcnt(10)" ::: "memory");                       \
        } else {                                                                    \
            asm volatile("s_waitcnt vmcnt(0)" ::: "memory");                        \
        }                                                                           \
        __builtin_amdgcn_s_barrier();   /* tile T visible to all waves */           \
        __builtin_amdgcn_s_setprio(1);                                              \
        _Pragma("unroll")                                                           \
        for (int kk = 0; kk < 2; kk++) {                                            \
            f16x8 af[4];                                                            \
            _Pragma("unroll")                                                       \
            for (int mi = 0; mi < 4; mi++)                                          \
                af[mi] = *reinterpret_cast<const f16x8*>(                           \
                    &As[BUF][(wr * 64 + mi * 16 + l15) * 64 + kk * 32 + g * 8]);    \
            _Pragma("unroll")                                                       \
            for (int ni = 0; ni < 6; ni++) {                                        \
                f16x8 bf = *reinterpret_cast<const f16x8*>(                         \
                    &Bs[BUF][(wc * 96 + ni * 16 + l15) * 64 + kk * 32 + g * 8]);    \
                _Pragma("unroll")                                                   \
                for (int mi = 0; mi < 4; mi++)                                      \
                    acc[mi][ni] = MFMA16(af[mi], bf, acc[mi][ni], 0, 0, 0);         \
            }                                                                       \
        }                                                                           \
        __builtin_amdgcn_s_setprio(0);                                              \
        __builtin_amdgcn_s_barrier();   /* buf BUF free for restage */              \
    }

    STAGE(0, 0)
    for (int t = 0; t < 16; t += 2) {
        KSTEP(t, 0)
        KSTEP(t + 1, 1)
    }
#undef KSTEP
#undef STAGE

    const int b = row0 >> 11;
    const int t0b = (row0 & (T_ - 1)) + wr * 64;
    #pragma unroll
    for (int ni = 0; ni < 6; ni++) {
        const int n = n0 + wc * 96 + ni * 16;
        const int region = n >> 10;             // 0=Q, 1=K, 2=V (wave-uniform)
        const int h = (n >> 6) & 15;
        const int d0 = n & 63;
        if (region < 2) {
            _Float16* dst = region ? Kf : Qf;
            const float osc = region ? 1.0f : SCALE2;
            const size_t hb = ((size_t)(b * H_ + h)) * T_ * D_;
            #pragma unroll
            for (int mi = 0; mi < 4; mi++)
                #pragma unroll
                for (int r = 0; r < 4; r++) {
                    int t = t0b + mi * 16 + g * 4 + r;
                    dst[hb + (size_t)t * D_ + d0 + l15] = (_Float16)(acc[mi][ni][r] * osc);
                }
        } else {
            const size_t vbase = ((size_t)(b * H_ + h)) * D_ * T_;
            const int d = d0 + l15;
            #pragma unroll
            for (int mi = 0; mi < 4; mi++) {
                int t = t0b + mi * 16 + g * 4;
                uint2 w;
                w.x = pk2(acc[mi][ni][0], acc[mi][ni][1]);
                w.y = pk2(acc[mi][ni][2], acc[mi][ni][3]);
                *reinterpret_cast<uint2*>((unsigned short*)Vt + vbase + (size_t)d * T_ + t) = w;
            }
        }
    }
}

// ---------------------------------------------------------------------------
// flash: causal attention, 128-kv super-tiles (dbuf K+V), two 64-kv sub-tiles,
// 1 barrier per super-tile.  grid(64 bh, 8 p) paired-uniform.
// Mask hoisted to last-sub-tile-only; row-sum on the matrix pipe.
// ---------------------------------------------------------------------------
__global__ __launch_bounds__(256) void flash_kernel(
    const _Float16* __restrict__ Qf, const _Float16* __restrict__ Kf,
    const _Float16* __restrict__ Vt, _Float16* __restrict__ att)
{
    __shared__ __align__(16) unsigned short Ks[2][128 * 64];  // [buf][kv][d]  128B rows
    __shared__ __align__(16) unsigned short Vs[2][64 * 128];  // [buf][d][kv]  256B rows
    __shared__ __align__(16) unsigned short Ps[4][32 * 32];   // per-wave P kv-half
    const int bh = blockIdx.x;
    const int p = (int)blockIdx.y;           // 0..7
    const int bb = bh >> 4, h = bh & 15;
    const int tid = threadIdx.x, wid = tid >> 6, lane = tid & 63;
    const int l15 = lane & 15, g = lane >> 4;

    const _Float16* Qb = Qf + (size_t)bh * T_ * D_;
    const _Float16* Kb = Kf + (size_t)bh * T_ * D_;
    const _Float16* Vb = Vt + (size_t)bh * D_ * T_;

    const int srow = lane >> 3;                  // K staging
    const int sunit = (lane & 7) ^ srow;
    const int r0k = wid * 32;
    const int vsrow = lane >> 4;                 // V staging (256B rows)
    const int r0v = wid * 16;

    char* const pbase = (char*)&Ps[wid][0];

    f16x8 ones;
    #pragma unroll
    for (int j = 0; j < 8; j++) ones[j] = (_Float16)1.0f;

    for (int pass = 0; pass < 2; pass++) {
        const int qt = pass ? p : (15 - p);
        const int q0 = qt * 128;
        const int qw = q0 + wid * 32;

        f16x8 qf[2][2];
        #pragma unroll
        for (int mt = 0; mt < 2; mt++)
            #pragma unroll
            for (int kk = 0; kk < 2; kk++)
                qf[mt][kk] = *reinterpret_cast<const f16x8*>(Qb + (size_t)(qw + mt * 16 + l15) * D_ + kk * 32 + g * 8);

        f32x4 accO[4][2];
        #pragma unroll
        for (int nt = 0; nt < 4; nt++)
            #pragma unroll
            for (int mt = 0; mt < 2; mt++) { f32x4 z = {0.f,0.f,0.f,0.f}; accO[nt][mt] = z; }
        float m[2] = { -1e30f, -1e30f };
        float l[2] = { 0.f, 0.f };

        const int nSup = qt + 1;                 // super-tiles (wave-uniform)
        const int mySub = (qw + 95) >> 6;        // 64-kv sub-tiles this wave computes

        // prologue: stage super-tile 0 into buf 0
        #pragma unroll
        for (int i = 0; i < 4; i++) {
            int krow = r0k + i * 8 + srow;
            gl_lds16(Kb + (size_t)krow * D_ + sunit * 8, &Ks[0][(r0k + i * 8) * 64]);
            int vrow = r0v + i * 4 + vsrow;
            int vsunit = (lane & 15) ^ (vrow & 7);
            gl_lds16(Vb + (size_t)vrow * T_ + vsunit * 8, &Vs[0][(r0v + i * 4) * 128]);
        }
        __syncthreads();

#define SUB_TILE(SP, SH, MASKED)                                                    \
    {                                                                               \
        const int kv0 = ((SP) * 2 + (SH)) * 64;                                     \
        f32x4 s[4][2];                                                              \
        _Pragma("unroll")                                                           \
        for (int st = 0; st < 4; st++)                                              \
            _Pragma("unroll")                                                       \
            for (int mt = 0; mt < 2; mt++) { f32x4 z = {0.f,0.f,0.f,0.f}; s[st][mt] = z; } \
        _Pragma("unroll")                                                           \
        for (int kk = 0; kk < 2; kk++) {                                            \
            f16x8 kfr[4];                                                           \
            _Pragma("unroll")                                                       \
            for (int st = 0; st < 4; st++) {                                        \
                int row = (SH) * 64 + st * 16 + l15;                                \
                kfr[st] = *reinterpret_cast<const f16x8*>(                          \
                    kb128 + row * 128 + (((kk * 4 + g) ^ (row & 7)) * 16));         \
            }                                                                       \
            _Pragma("unroll")                                                       \
            for (int st = 0; st < 4; st++)                                          \
                _Pragma("unroll")                                                   \
                for (int mt = 0; mt < 2; mt++)                                      \
                    s[st][mt] = MFMA16(kfr[st], qf[mt][kk], s[st][mt], 0, 0, 0);    \
        }                                                                           \
        unsigned pw[2][4][2];                                                       \
        _Pragma("unroll")                                                           \
        for (int mt = 0; mt < 2; mt++) {                                            \
            if (MASKED) {                                                           \
                const int qrow = qw + mt * 16 + l15;                                \
                _Pragma("unroll")                                                   \
                for (int st = 0; st < 4; st++)                                      \
                    _Pragma("unroll")                                               \
                    for (int rr = 0; rr < 4; rr++) {                                \
                        int kv = kv0 + st * 16 + g * 4 + rr;                        \
                        s[st][mt][rr] = (kv <= qrow) ? s[st][mt][rr] : -1e30f;      \
                    }                                                               \
            }                                                                       \
            float vmax = -1e30f;                                                    \
            _Pragma("unroll")                                                       \
            for (int st = 0; st < 4; st++)                                          \
                _Pragma("unroll")                                                   \
                for (int rr = 0; rr < 4; rr++)                                      \
                    vmax = fmaxf(vmax, s[st][mt][rr]);                              \
            vmax = fmaxf(vmax, __shfl_xor(vmax, 16, 64));                           \
            vmax = fmaxf(vmax, __shfl_xor(vmax, 32, 64));                           \
            if (__any(vmax > m[mt])) {                                              \
                float mnew = fmaxf(m[mt], vmax);                                    \
                float alpha = __builtin_amdgcn_exp2f(m[mt] - mnew);                 \
                m[mt] = mnew;                                                       \
                l[mt] *= alpha;                                                     \
                _Pragma("unroll")                                                   \
                for (int nt = 0; nt < 4; nt++) accO[nt][mt] *= alpha;               \
            }                                                                       \
            _Pragma("unroll")                                                       \
            for (int st = 0; st < 4; st++) {                                        \
                float p0 = __builtin_amdgcn_exp2f(s[st][mt][0] - m[mt]);            \
                float p1 = __builtin_amdgcn_exp2f(s[st][mt][1] - m[mt]);            \
                float p2 = __builtin_amdgcn_exp2f(s[st][mt][2] - m[mt]);            \
                float p3 = __builtin_amdgcn_exp2f(s[st][mt][3] - m[mt]);            \
                pw[mt][st][0] = pk2(p0, p1);                                        \
                pw[mt][st][1] = pk2(p2, p3);                                        \
            }                                                                       \
        }                                                                           \
        f32x4 rsacc[2];                                                             \
        { f32x4 z = {0.f,0.f,0.f,0.f}; rsacc[0] = z; rsacc[1] = z; }                \
        _Pragma("unroll")                                                           \
        for (int ph = 0; ph < 2; ph++) {                                            \
            _Pragma("unroll")                                                       \
            for (int mt = 0; mt < 2; mt++) {                                        \
                const int r = mt * 16 + l15;                                        \
                const int swz = ((r >> 1) & 3) << 4;                                \
                char* prow = pbase + r * 64;                                        \
                _Pragma("unroll")                                                   \
                for (int stl = 0; stl < 2; stl++) {                                 \
                    uint2 w;                                                        \
                    w.x = pw[mt][ph * 2 + stl][0];                                  \
                    w.y = pw[mt][ph * 2 + stl][1];                                  \
                    *reinterpret_cast<uint2*>(prow + ((stl * 32 + g * 8) ^ swz)) = w; \
                }                                                                   \
            }                                                                       \
            f16x8 pb[2];                                                            \
            _Pragma("unroll")                                                       \
            for (int mt = 0; mt < 2; mt++) {                                        \
                const int r = mt * 16 + l15;                                        \
                const int swz = ((r >> 1) & 3) << 4;                                \
                pb[mt] = *reinterpret_cast<const f16x8*>(pbase + r * 64 + ((g * 16) ^ swz)); \
            }                                                                       \
            rsacc[0] = MFMA16(ones, pb[0], rsacc[0], 0, 0, 0);                      \
            rsacc[1] = MFMA16(ones, pb[1], rsacc[1], 0, 0, 0);                      \
            _Pragma("unroll")                                                       \
            for (int nt = 0; nt < 4; nt++) {                                        \
                int row = nt * 16 + l15;                                            \
                int unit = ((SH) * 8 + ph * 4 + g) ^ (row & 7);                     \
                f16x8 vf = *reinterpret_cast<const f16x8*>(                         \
                    vb128 + row * 256 + unit * 16);                                 \
                _Pragma("unroll")                                                   \
                for (int mt = 0; mt < 2; mt++)                                      \
                    accO[nt][mt] = MFMA16(vf, pb[mt], accO[nt][mt], 0, 0, 0);       \
            }                                                                       \
        }                                                                           \
        l[0] += rsacc[0][0];                                                        \
        l[1] += rsacc[1][0];                                                        \
    }

#define SUPER_BODY(SP, BUF)                                                         \
    {                                                                               \
        if ((SP) + 1 < nSup) {                                                      \
            const int kvn = ((SP) + 1) * 128;                                       \
            _Pragma("unroll")                                                       \
            for (int i = 0; i < 4; i++) {                                           \
                int krow = r0k + i * 8 + srow;                                      \
                gl_lds16(Kb + (size_t)(kvn + krow) * D_ + sunit * 8,                \
                         &Ks[(BUF) ^ 1][(r0k + i * 8) * 64]);                       \
                int vrow = r0v + i * 4 + vsrow;                                     \
                int vsunit = (lane & 15) ^ (vrow & 7);                              \
                gl_lds16(Vb + (size_t)vrow * T_ + kvn + vsunit * 8,                 \
                         &Vs[(BUF) ^ 1][(r0v + i * 4) * 128]);                      \
            }                                                                       \
        }                                                                           \
        const char* kb128 = (const char*)&Ks[BUF][0];                               \
        const char* vb128 = (const char*)&Vs[BUF][0];                               \
        if ((SP) * 2 + 1 < mySub)      { SUB_TILE(SP, 0, 0) }                       \
        else if ((SP) * 2 < mySub)     { SUB_TILE(SP, 0, 1) }                       \
        if ((SP) * 2 + 2 < mySub)      { SUB_TILE(SP, 1, 0) }                       \
        else if ((SP) * 2 + 1 < mySub) { SUB_TILE(SP, 1, 1) }                       \
        __syncthreads();                                                            \
    }

        for (int sp = 0; sp < nSup; sp += 2) {
            SUPER_BODY(sp, 0)
            if (sp + 1 < nSup) {
                SUPER_BODY(sp + 1, 1)
            }
        }
#undef SUPER_BODY
#undef SUB_TILE

        // epilogue: normalize, write att [b][t][h*64+d] fp16
        #pragma unroll
        for (int mt = 0; mt < 2; mt++) {
            float inv = 1.0f / l[mt];
            int t = qw + mt * 16 + l15;
            #pragma unroll
            for (int nt = 0; nt < 4; nt++) {
                f32x4 o = accO[nt][mt] * inv;
                uint2 w;
                w.x = pk2(o[0], o[1]);
                w.y = pk2(o[2], o[3]);
                size_t off = ((size_t)(bb * T_ + t)) * (H_ * D_) + h * D_ + nt * 16 + g * 4;
                *reinterpret_cast<uint2*>((unsigned short*)att + off) = w;
            }
        }
    }
}

// ---------------------------------------------------------------------------
// proj2: m97-style LDS GEMM.  out = att[8192x1024] @ Wpt^T + bp.
// grid(64, 8), block 256 (4 waves, 2x2).  128x128 tile, BK=64.
// ---------------------------------------------------------------------------
__global__ __launch_bounds__(256) void proj2_kernel(
    const _Float16* __restrict__ att, const _Float16* __restrict__ Wpt,
    const float* __restrict__ bp, float* __restrict__ out)
{
    __shared__ unsigned short As[128 * 64];
    __shared__ unsigned short Bs[128 * 64];
    const int rt = blockIdx.x, ct = blockIdx.y;
    const int row0 = rt * 128, n0 = ct * 128;
    const int tid = threadIdx.x, wid = tid >> 6, lane = tid & 63;
    const int l15 = lane & 15, g = lane >> 4;
    const int wr = wid >> 1, wc = wid & 1;
    const int lrow = lane >> 3, lcol = (lane & 7) * 8;

    f32x4 acc[4][4];
    #pragma unroll
    for (int mi = 0; mi < 4; mi++)
        #pragma unroll
        for (int ni = 0; ni < 4; ni++) { f32x4 z = {0.f,0.f,0.f,0.f}; acc[mi][ni] = z; }

    for (int k0 = 0; k0 < C_; k0 += 64) {
        __syncthreads();
        #pragma unroll
        for (int i = 0; i < 4; i++) {
            int c = wid * 4 + i;
            gl_lds16(att + (size_t)(row0 + c * 8 + lrow) * C_ + k0 + lcol, &As[c * 512]);
            gl_lds16(Wpt + (size_t)(n0   + c * 8 + lrow) * C_ + k0 + lcol, &Bs[c * 512]);
        }
        __syncthreads();
        #pragma unroll
        for (int kk = 0; kk < 2; kk++) {
            f16x8 af[4], bf[4];
            #pragma unroll
            for (int mi = 0; mi < 4; mi++)
                af[mi] = *reinterpret_cast<const f16x8*>(&As[(wr * 64 + mi * 16 + l15) * 64 + kk * 32 + g * 8]);
            #pragma unroll
            for (int ni = 0; ni < 4; ni++)
                bf[ni] = *reinterpret_cast<const f16x8*>(&Bs[(wc * 64 + ni * 16 + l15) * 64 + kk * 32 + g * 8]);
            #pragma unroll
            for (int mi = 0; mi < 4; mi++)
                #pragma unroll
                for (int ni = 0; ni < 4; ni++)
                    acc[mi][ni] = MFMA16(af[mi], bf[ni], acc[mi][ni], 0, 0, 0);
        }
    }

    #pragma unroll
    for (int mi = 0; mi < 4; mi++)
        #pragma unroll
        for (int ni = 0; ni < 4; ni++) {
            int col = n0 + wc * 64 + ni * 16 + l15;
            float bias = bp[col];
            #pragma unroll
            for (int r = 0; r < 4; r++) {
                int row = row0 + wr * 64 + mi * 16 + g * 4 + r;
                out[(size_t)row * C_ + col] = acc[mi][ni][r] + bias;
            }
        }
}

// ---------------------------------------------------------------------------
extern "C" void kernel_launch(void* const* d_in, const int* in_sizes, int n_in,
                              void* d_out, int out_size, void* d_ws, size_t ws_size,
                              hipStream_t stream) {
    const float* x  = (const float*)d_in[0];
    const float* Wq = (const float*)d_in[1];
    const float* Wk = (const float*)d_in[2];
    const float* Wv = (const float*)d_in[3];
    const float* Wp = (const float*)d_in[4];
    const float* bp = (const float*)d_in[5];
    float* out = (float*)d_out;

    _Float16* Xf  = (_Float16*)d_ws;                 // 8192x1024
    _Float16* Wqt = Xf  + (size_t)8388608;           // 16x64x1024  } contiguous =
    _Float16* Wkt = Wqt + (size_t)1048576;           //             } Wcat[3072][1024]
    _Float16* Wvt = Wkt + (size_t)1048576;           //             }
    _Float16* Wpt = Wvt + (size_t)1048576;           // 1024x1024 (transposed)
    _Float16* Qf  = Wpt + (size_t)1048576;           // 64x2048x64  (pre-scaled)
    _Float16* Kf  = Qf  + (size_t)8388608;
    _Float16* Vt  = Kf  + (size_t)8388608;           // 64x64x2048 (transposed)
    _Float16* att = Vt  + (size_t)8388608;           // 4x2048x1024

    convx_kernel<<<4096, 256, 0, stream>>>(x, Xf);
    convw_qkv_kernel<<<dim3(8, 16, 3), 256, 0, stream>>>(Wq, Wk, Wv, Wqt, Wkt, Wvt);
    convw_p_kernel<<<dim3(16, 16), 256, 0, stream>>>(Wp, Wpt);
    qkv5_kernel<<<dim3(64, 16), 256, 0, stream>>>(Xf, Wqt, Qf, Kf, Vt);
    flash_kernel<<<dim3(64, 8), 256, 0, stream>>>(Qf, Kf, Vt, att);
    proj2_kernel<<<dim3(64, 8), 256, 0, stream>>>(att, Wpt, bp, out);
}

// Round 18
// 184.585 us; speedup vs baseline: 1.2083x; 1.2083x over previous
//
#include <hip/hip_runtime.h>

#define B_ 4
#define T_ 2048
#define C_ 1024
#define H_ 16
#define D_ 64

typedef _Float16 f16x8 __attribute__((ext_vector_type(8)));
typedef __fp16 fp16x2 __attribute__((ext_vector_type(2)));
typedef float f32x4 __attribute__((ext_vector_type(4)));
typedef unsigned short u16x8 __attribute__((ext_vector_type(8)));

#define MFMA16 __builtin_amdgcn_mfma_f32_16x16x32_f16
#define SCALE2 11.541560327111707f   /* 8 * log2(e), pre-folded into Q */

__device__ __forceinline__ unsigned pk2(float a, float b) {
    fp16x2 p = __builtin_amdgcn_cvt_pkrtz(a, b);
    return __builtin_bit_cast(unsigned, p);
}

__device__ __forceinline__ void gl_lds16(const _Float16* g, unsigned short* lds) {
    __builtin_amdgcn_global_load_lds(
        (const __attribute__((address_space(1))) unsigned int*)g,
        (__attribute__((address_space(3))) unsigned int*)lds, 16, 0, 0);
}

// ---------------------------------------------------------------------------
// convx: x fp32 -> Xf fp16.  grid 4096, block 256.
// ---------------------------------------------------------------------------
__global__ __launch_bounds__(256) void convx_kernel(const float* __restrict__ x,
                                                    _Float16* __restrict__ Xf) {
    size_t i = ((size_t)blockIdx.x * 256 + threadIdx.x) * 8;
    f32x4 a = *reinterpret_cast<const f32x4*>(x + i);
    f32x4 b = *reinterpret_cast<const f32x4*>(x + i + 4);
    f16x8 o;
    o[0] = (_Float16)a[0]; o[1] = (_Float16)a[1]; o[2] = (_Float16)a[2]; o[3] = (_Float16)a[3];
    o[4] = (_Float16)b[0]; o[5] = (_Float16)b[1]; o[6] = (_Float16)b[2]; o[7] = (_Float16)b[3];
    *reinterpret_cast<f16x8*>(Xf + i) = o;
}

// ---------------------------------------------------------------------------
// convw_qkv: W[h][c][d] fp32 -> Wt[h][d][c] fp16 (transposed).  grid(8,16,3).
// ---------------------------------------------------------------------------
__global__ __launch_bounds__(256) void convw_qkv_kernel(
    const float* __restrict__ Wq, const float* __restrict__ Wk, const float* __restrict__ Wv,
    _Float16* __restrict__ Wqt, _Float16* __restrict__ Wkt, _Float16* __restrict__ Wvt)
{
    __shared__ unsigned short Wl[128][72];
    const int ct = blockIdx.x, h = blockIdx.y, m = blockIdx.z;
    const float* src = (m == 0 ? Wq : (m == 1 ? Wk : Wv)) + ((size_t)h * C_ + ct * 128) * D_;
    _Float16* dst = (m == 0 ? Wqt : (m == 1 ? Wkt : Wvt));
    const int tid = threadIdx.x;
    {
        int r = tid >> 1, half = tid & 1;
        #pragma unroll
        for (int i = 0; i < 8; i++) {
            f32x4 v = *reinterpret_cast<const f32x4*>(src + (size_t)r * D_ + half * 32 + i * 4);
            #pragma unroll
            for (int j = 0; j < 4; j++)
                Wl[r][half * 32 + i * 4 + j] = __builtin_bit_cast(unsigned short, (_Float16)v[j]);
        }
    }
    __syncthreads();
    {
        int d = tid >> 2, seg = tid & 3;
        #pragma unroll
        for (int i = 0; i < 4; i++) {
            u16x8 o;
            #pragma unroll
            for (int j = 0; j < 8; j++) o[j] = Wl[seg * 32 + i * 8 + j][d];
            *reinterpret_cast<u16x8*>((unsigned short*)dst + ((size_t)h * D_ + d) * C_ + ct * 128 + seg * 32 + i * 8) = o;
        }
    }
}

// ---------------------------------------------------------------------------
// convw_p: Wp[k][j] fp32 -> Wpt[j][k] fp16.  grid(16,16).
// ---------------------------------------------------------------------------
__global__ __launch_bounds__(256) void convw_p_kernel(const float* __restrict__ Wp,
                                                      _Float16* __restrict__ Wpt)
{
    __shared__ unsigned short Pl[64][72];
    const int jt = blockIdx.x, kt = blockIdx.y;
    const int tid = threadIdx.x;
    {
        int r = tid >> 2, seg = tid & 3;
        #pragma unroll
        for (int i = 0; i < 4; i++) {
            f32x4 v = *reinterpret_cast<const f32x4*>(Wp + (size_t)(kt * 64 + r) * C_ + jt * 64 + seg * 16 + i * 4);
            #pragma unroll
            for (int j = 0; j < 4; j++)
                Pl[r][seg * 16 + i * 4 + j] = __builtin_bit_cast(unsigned short, (_Float16)v[j]);
        }
    }
    __syncthreads();
    {
        int jj = tid >> 2, kseg = tid & 3;
        #pragma unroll
        for (int i = 0; i < 2; i++) {
            u16x8 o;
            #pragma unroll
            for (int j = 0; j < 8; j++) o[j] = Pl[kseg * 16 + i * 8 + j][jj];
            *reinterpret_cast<u16x8*>((unsigned short*)Wpt + (size_t)(jt * 64 + jj) * C_ + kt * 64 + kseg * 16 + i * 8) = o;
        }
    }
}

// ---------------------------------------------------------------------------
// qkv4: X[8192x1024] @ Wcat^T[3072x1024], 128x192 tile, BK=64, 4 waves (2x2,
// per-wave 64x96).  grid(64, 16) = 1024 blocks = exactly 4 blocks/CU x 1 gen.
// (r17 lesson: dbuf+vmcnt pipelining at 2 blocks/CU regressed 81->116 µs —
// the T3/T4 gain requires the full 8-phase schedule, not a 2-phase graft.)
// ---------------------------------------------------------------------------
__global__ __launch_bounds__(256) void qkv4_kernel(
    const _Float16* __restrict__ Xf, const _Float16* __restrict__ Wcat,
    _Float16* __restrict__ Qf, _Float16* __restrict__ Kf, _Float16* __restrict__ Vt)
{
    __shared__ unsigned short As[128 * 64];
    __shared__ unsigned short Bs[192 * 64];
    const int rt = blockIdx.x, ct = blockIdx.y;
    const int row0 = rt * 128, n0 = ct * 192;
    const int tid = threadIdx.x, wid = tid >> 6, lane = tid & 63;
    const int l15 = lane & 15, g = lane >> 4;
    const int wr = wid >> 1, wc = wid & 1;
    const int lrow = lane >> 3, lcol = (lane & 7) * 8;

    f32x4 acc[4][6];
    #pragma unroll
    for (int mi = 0; mi < 4; mi++)
        #pragma unroll
        for (int ni = 0; ni < 6; ni++) { f32x4 z = {0.f,0.f,0.f,0.f}; acc[mi][ni] = z; }

    for (int k0 = 0; k0 < C_; k0 += 64) {
        __syncthreads();
        #pragma unroll
        for (int i = 0; i < 4; i++) {
            int c = wid * 4 + i;
            gl_lds16(Xf + (size_t)(row0 + c * 8 + lrow) * C_ + k0 + lcol, &As[c * 512]);
        }
        #pragma unroll
        for (int i = 0; i < 6; i++) {
            int c = wid * 6 + i;
            gl_lds16(Wcat + (size_t)(n0 + c * 8 + lrow) * C_ + k0 + lcol, &Bs[c * 512]);
        }
        __syncthreads();
        #pragma unroll
        for (int kk = 0; kk < 2; kk++) {
            f16x8 af[4];
            #pragma unroll
            for (int mi = 0; mi < 4; mi++)
                af[mi] = *reinterpret_cast<const f16x8*>(&As[(wr * 64 + mi * 16 + l15) * 64 + kk * 32 + g * 8]);
            #pragma unroll
            for (int ni = 0; ni < 6; ni++) {
                f16x8 bf = *reinterpret_cast<const f16x8*>(&Bs[(wc * 96 + ni * 16 + l15) * 64 + kk * 32 + g * 8]);
                #pragma unroll
                for (int mi = 0; mi < 4; mi++)
                    acc[mi][ni] = MFMA16(af[mi], bf, acc[mi][ni], 0, 0, 0);
            }
        }
    }

    const int b = row0 >> 11;
    const int t0b = (row0 & (T_ - 1)) + wr * 64;
    #pragma unroll
    for (int ni = 0; ni < 6; ni++) {
        const int n = n0 + wc * 96 + ni * 16;
        const int region = n >> 10;             // 0=Q, 1=K, 2=V (wave-uniform)
        const int h = (n >> 6) & 15;
        const int d0 = n & 63;
        if (region < 2) {
            _Float16* dst = region ? Kf : Qf;
            const float osc = region ? 1.0f : SCALE2;
            const size_t hb = ((size_t)(b * H_ + h)) * T_ * D_;
            #pragma unroll
            for (int mi = 0; mi < 4; mi++)
                #pragma unroll
                for (int r = 0; r < 4; r++) {
                    int t = t0b + mi * 16 + g * 4 + r;
                    dst[hb + (size_t)t * D_ + d0 + l15] = (_Float16)(acc[mi][ni][r] * osc);
                }
        } else {
            const size_t vbase = ((size_t)(b * H_ + h)) * D_ * T_;
            const int d = d0 + l15;
            #pragma unroll
            for (int mi = 0; mi < 4; mi++) {
                int t = t0b + mi * 16 + g * 4;
                uint2 w;
                w.x = pk2(acc[mi][ni][0], acc[mi][ni][1]);
                w.y = pk2(acc[mi][ni][2], acc[mi][ni][3]);
                *reinterpret_cast<uint2*>((unsigned short*)Vt + vbase + (size_t)d * T_ + t) = w;
            }
        }
    }
}

// ---------------------------------------------------------------------------
// flash: causal attention, 128-kv super-tiles (dbuf K+V), two 64-kv sub-tiles,
// 1 barrier per super-tile.  grid(64 bh, 8 p) paired-uniform.
// Mask hoisted to last-sub-tile-only; row-sum on the matrix pipe.
// ---------------------------------------------------------------------------
__global__ __launch_bounds__(256) void flash_kernel(
    const _Float16* __restrict__ Qf, const _Float16* __restrict__ Kf,
    const _Float16* __restrict__ Vt, _Float16* __restrict__ att)
{
    __shared__ __align__(16) unsigned short Ks[2][128 * 64];  // [buf][kv][d]  128B rows
    __shared__ __align__(16) unsigned short Vs[2][64 * 128];  // [buf][d][kv]  256B rows
    __shared__ __align__(16) unsigned short Ps[4][32 * 32];   // per-wave P kv-half
    const int bh = blockIdx.x;
    const int p = (int)blockIdx.y;           // 0..7
    const int bb = bh >> 4, h = bh & 15;
    const int tid = threadIdx.x, wid = tid >> 6, lane = tid & 63;
    const int l15 = lane & 15, g = lane >> 4;

    const _Float16* Qb = Qf + (size_t)bh * T_ * D_;
    const _Float16* Kb = Kf + (size_t)bh * T_ * D_;
    const _Float16* Vb = Vt + (size_t)bh * D_ * T_;

    const int srow = lane >> 3;                  // K staging
    const int sunit = (lane & 7) ^ srow;
    const int r0k = wid * 32;
    const int vsrow = lane >> 4;                 // V staging (256B rows)
    const int r0v = wid * 16;

    char* const pbase = (char*)&Ps[wid][0];

    f16x8 ones;
    #pragma unroll
    for (int j = 0; j < 8; j++) ones[j] = (_Float16)1.0f;

    for (int pass = 0; pass < 2; pass++) {
        const int qt = pass ? p : (15 - p);
        const int q0 = qt * 128;
        const int qw = q0 + wid * 32;

        f16x8 qf[2][2];
        #pragma unroll
        for (int mt = 0; mt < 2; mt++)
            #pragma unroll
            for (int kk = 0; kk < 2; kk++)
                qf[mt][kk] = *reinterpret_cast<const f16x8*>(Qb + (size_t)(qw + mt * 16 + l15) * D_ + kk * 32 + g * 8);

        f32x4 accO[4][2];
        #pragma unroll
        for (int nt = 0; nt < 4; nt++)
            #pragma unroll
            for (int mt = 0; mt < 2; mt++) { f32x4 z = {0.f,0.f,0.f,0.f}; accO[nt][mt] = z; }
        float m[2] = { -1e30f, -1e30f };
        float l[2] = { 0.f, 0.f };

        const int nSup = qt + 1;                 // super-tiles (wave-uniform)
        const int mySub = (qw + 95) >> 6;        // 64-kv sub-tiles this wave computes

        // prologue: stage super-tile 0 into buf 0
        #pragma unroll
        for (int i = 0; i < 4; i++) {
            int krow = r0k + i * 8 + srow;
            gl_lds16(Kb + (size_t)krow * D_ + sunit * 8, &Ks[0][(r0k + i * 8) * 64]);
            int vrow = r0v + i * 4 + vsrow;
            int vsunit = (lane & 15) ^ (vrow & 7);
            gl_lds16(Vb + (size_t)vrow * T_ + vsunit * 8, &Vs[0][(r0v + i * 4) * 128]);
        }
        __syncthreads();

#define SUB_TILE(SP, SH, MASKED)                                                    \
    {                                                                               \
        const int kv0 = ((SP) * 2 + (SH)) * 64;                                     \
        f32x4 s[4][2];                                                              \
        _Pragma("unroll")                                                           \
        for (int st = 0; st < 4; st++)                                              \
            _Pragma("unroll")                                                       \
            for (int mt = 0; mt < 2; mt++) { f32x4 z = {0.f,0.f,0.f,0.f}; s[st][mt] = z; } \
        _Pragma("unroll")                                                           \
        for (int kk = 0; kk < 2; kk++) {                                            \
            f16x8 kfr[4];                                                           \
            _Pragma("unroll")                                                       \
            for (int st = 0; st < 4; st++) {                                        \
                int row = (SH) * 64 + st * 16 + l15;                                \
                kfr[st] = *reinterpret_cast<const f16x8*>(                          \
                    kb128 + row * 128 + (((kk * 4 + g) ^ (row & 7)) * 16));         \
            }                                                                       \
            _Pragma("unroll")                                                       \
            for (int st = 0; st < 4; st++)                                          \
                _Pragma("unroll")                                                   \
                for (int mt = 0; mt < 2; mt++)                                      \
                    s[st][mt] = MFMA16(kfr[st], qf[mt][kk], s[st][mt], 0, 0, 0);    \
        }                                                                           \
        unsigned pw[2][4][2];                                                       \
        _Pragma("unroll")                                                           \
        for (int mt = 0; mt < 2; mt++) {                                            \
            if (MASKED) {                                                           \
                const int qrow = qw + mt * 16 + l15;                                \
                _Pragma("unroll")                                                   \
                for (int st = 0; st < 4; st++)                                      \
                    _Pragma("unroll")                                               \
                    for (int rr = 0; rr < 4; rr++) {                                \
                        int kv = kv0 + st * 16 + g * 4 + rr;                        \
                        s[st][mt][rr] = (kv <= qrow) ? s[st][mt][rr] : -1e30f;      \
                    }                                                               \
            }                                                                       \
            float vmax = -1e30f;                                                    \
            _Pragma("unroll")                                                       \
            for (int st = 0; st < 4; st++)                                          \
                _Pragma("unroll")                                                   \
                for (int rr = 0; rr < 4; rr++)                                      \
                    vmax = fmaxf(vmax, s[st][mt][rr]);                              \
            vmax = fmaxf(vmax, __shfl_xor(vmax, 16, 64));                           \
            vmax = fmaxf(vmax, __shfl_xor(vmax, 32, 64));                           \
            if (__any(vmax > m[mt])) {                                              \
                float mnew = fmaxf(m[mt], vmax);                                    \
                float alpha = __builtin_amdgcn_exp2f(m[mt] - mnew);                 \
                m[mt] = mnew;                                                       \
                l[mt] *= alpha;                                                     \
                _Pragma("unroll")                                                   \
                for (int nt = 0; nt < 4; nt++) accO[nt][mt] *= alpha;               \
            }                                                                       \
            _Pragma("unroll")                                                       \
            for (int st = 0; st < 4; st++) {                                        \
                float p0 = __builtin_amdgcn_exp2f(s[st][mt][0] - m[mt]);            \
                float p1 = __builtin_amdgcn_exp2f(s[st][mt][1] - m[mt]);            \
                float p2 = __builtin_amdgcn_exp2f(s[st][mt][2] - m[mt]);            \
                float p3 = __builtin_amdgcn_exp2f(s[st][mt][3] - m[mt]);            \
                pw[mt][st][0] = pk2(p0, p1);                                        \
                pw[mt][st][1] = pk2(p2, p3);                                        \
            }                                                                       \
        }                                                                           \
        f32x4 rsacc[2];                                                             \
        { f32x4 z = {0.f,0.f,0.f,0.f}; rsacc[0] = z; rsacc[1] = z; }                \
        _Pragma("unroll")                                                           \
        for (int ph = 0; ph < 2; ph++) {                                            \
            _Pragma("unroll")                                                       \
            for (int mt = 0; mt < 2; mt++) {                                        \
                const int r = mt * 16 + l15;                                        \
                const int swz = ((r >> 1) & 3) << 4;                                \
                char* prow = pbase + r * 64;                                        \
                _Pragma("unroll")                                                   \
                for (int stl = 0; stl < 2; stl++) {                                 \
                    uint2 w;                                                        \
                    w.x = pw[mt][ph * 2 + stl][0];                                  \
                    w.y = pw[mt][ph * 2 + stl][1];                                  \
                    *reinterpret_cast<uint2*>(prow + ((stl * 32 + g * 8) ^ swz)) = w; \
                }                                                                   \
            }                                                                       \
            f16x8 pb[2];                                                            \
            _Pragma("unroll")                                                       \
            for (int mt = 0; mt < 2; mt++) {                                        \
                const int r = mt * 16 + l15;                                        \
                const int swz = ((r >> 1) & 3) << 4;                                \
                pb[mt] = *reinterpret_cast<const f16x8*>(pbase + r * 64 + ((g * 16) ^ swz)); \
            }                                                                       \
            rsacc[0] = MFMA16(ones, pb[0], rsacc[0], 0, 0, 0);                      \
            rsacc[1] = MFMA16(ones, pb[1], rsacc[1], 0, 0, 0);                      \
            _Pragma("unroll")                                                       \
            for (int nt = 0; nt < 4; nt++) {                                        \
                int row = nt * 16 + l15;                                            \
                int unit = ((SH) * 8 + ph * 4 + g) ^ (row & 7);                     \
                f16x8 vf = *reinterpret_cast<const f16x8*>(                         \
                    vb128 + row * 256 + unit * 16);                                 \
                _Pragma("unroll")                                                   \
                for (int mt = 0; mt < 2; mt++)                                      \
                    accO[nt][mt] = MFMA16(vf, pb[mt], accO[nt][mt], 0, 0, 0);       \
            }                                                                       \
        }                                                                           \
        l[0] += rsacc[0][0];                                                        \
        l[1] += rsacc[1][0];                                                        \
    }

#define SUPER_BODY(SP, BUF)                                                         \
    {                                                                               \
        if ((SP) + 1 < nSup) {                                                      \
            const int kvn = ((SP) + 1) * 128;                                       \
            _Pragma("unroll")                                                       \
            for (int i = 0; i < 4; i++) {                                           \
                int krow = r0k + i * 8 + srow;                                      \
                gl_lds16(Kb + (size_t)(kvn + krow) * D_ + sunit * 8,                \
                         &Ks[(BUF) ^ 1][(r0k + i * 8) * 64]);                       \
                int vrow = r0v + i * 4 + vsrow;                                     \
                int vsunit = (lane & 15) ^ (vrow & 7);                              \
                gl_lds16(Vb + (size_t)vrow * T_ + kvn + vsunit * 8,                 \
                         &Vs[(BUF) ^ 1][(r0v + i * 4) * 128]);                      \
            }                                                                       \
        }                                                                           \
        const char* kb128 = (const char*)&Ks[BUF][0];                               \
        const char* vb128 = (const char*)&Vs[BUF][0];                               \
        if ((SP) * 2 + 1 < mySub)      { SUB_TILE(SP, 0, 0) }                       \
        else if ((SP) * 2 < mySub)     { SUB_TILE(SP, 0, 1) }                       \
        if ((SP) * 2 + 2 < mySub)      { SUB_TILE(SP, 1, 0) }                       \
        else if ((SP) * 2 + 1 < mySub) { SUB_TILE(SP, 1, 1) }                       \
        __syncthreads();                                                            \
    }

        for (int sp = 0; sp < nSup; sp += 2) {
            SUPER_BODY(sp, 0)
            if (sp + 1 < nSup) {
                SUPER_BODY(sp + 1, 1)
            }
        }
#undef SUPER_BODY
#undef SUB_TILE

        // epilogue: normalize, write att [b][t][h*64+d] fp16
        #pragma unroll
        for (int mt = 0; mt < 2; mt++) {
            float inv = 1.0f / l[mt];
            int t = qw + mt * 16 + l15;
            #pragma unroll
            for (int nt = 0; nt < 4; nt++) {
                f32x4 o = accO[nt][mt] * inv;
                uint2 w;
                w.x = pk2(o[0], o[1]);
                w.y = pk2(o[2], o[3]);
                size_t off = ((size_t)(bb * T_ + t)) * (H_ * D_) + h * D_ + nt * 16 + g * 4;
                *reinterpret_cast<uint2*>((unsigned short*)att + off) = w;
            }
        }
    }
}

// ---------------------------------------------------------------------------
// proj2: m97-style LDS GEMM.  out = att[8192x1024] @ Wpt^T + bp.
// grid(64, 8), block 256 (4 waves, 2x2).  128x128 tile, BK=64.
// ---------------------------------------------------------------------------
__global__ __launch_bounds__(256) void proj2_kernel(
    const _Float16* __restrict__ att, const _Float16* __restrict__ Wpt,
    const float* __restrict__ bp, float* __restrict__ out)
{
    __shared__ unsigned short As[128 * 64];
    __shared__ unsigned short Bs[128 * 64];
    const int rt = blockIdx.x, ct = blockIdx.y;
    const int row0 = rt * 128, n0 = ct * 128;
    const int tid = threadIdx.x, wid = tid >> 6, lane = tid & 63;
    const int l15 = lane & 15, g = lane >> 4;
    const int wr = wid >> 1, wc = wid & 1;
    const int lrow = lane >> 3, lcol = (lane & 7) * 8;

    f32x4 acc[4][4];
    #pragma unroll
    for (int mi = 0; mi < 4; mi++)
        #pragma unroll
        for (int ni = 0; ni < 4; ni++) { f32x4 z = {0.f,0.f,0.f,0.f}; acc[mi][ni] = z; }

    for (int k0 = 0; k0 < C_; k0 += 64) {
        __syncthreads();
        #pragma unroll
        for (int i = 0; i < 4; i++) {
            int c = wid * 4 + i;
            gl_lds16(att + (size_t)(row0 + c * 8 + lrow) * C_ + k0 + lcol, &As[c * 512]);
            gl_lds16(Wpt + (size_t)(n0   + c * 8 + lrow) * C_ + k0 + lcol, &Bs[c * 512]);
        }
        __syncthreads();
        #pragma unroll
        for (int kk = 0; kk < 2; kk++) {
            f16x8 af[4], bf[4];
            #pragma unroll
            for (int mi = 0; mi < 4; mi++)
                af[mi] = *reinterpret_cast<const f16x8*>(&As[(wr * 64 + mi * 16 + l15) * 64 + kk * 32 + g * 8]);
            #pragma unroll
            for (int ni = 0; ni < 4; ni++)
                bf[ni] = *reinterpret_cast<const f16x8*>(&Bs[(wc * 64 + ni * 16 + l15) * 64 + kk * 32 + g * 8]);
            #pragma unroll
            for (int mi = 0; mi < 4; mi++)
                #pragma unroll
                for (int ni = 0; ni < 4; ni++)
                    acc[mi][ni] = MFMA16(af[mi], bf[ni], acc[mi][ni], 0, 0, 0);
        }
    }

    #pragma unroll
    for (int mi = 0; mi < 4; mi++)
        #pragma unroll
        for (int ni = 0; ni < 4; ni++) {
            int col = n0 + wc * 64 + ni * 16 + l15;
            float bias = bp[col];
            #pragma unroll
            for (int r = 0; r < 4; r++) {
                int row = row0 + wr * 64 + mi * 16 + g * 4 + r;
                out[(size_t)row * C_ + col] = acc[mi][ni][r] + bias;
            }
        }
}

// ---------------------------------------------------------------------------
extern "C" void kernel_launch(void* const* d_in, const int* in_sizes, int n_in,
                              void* d_out, int out_size, void* d_ws, size_t ws_size,
                              hipStream_t stream) {
    const float* x  = (const float*)d_in[0];
    const float* Wq = (const float*)d_in[1];
    const float* Wk = (const float*)d_in[2];
    const float* Wv = (const float*)d_in[3];
    const float* Wp = (const float*)d_in[4];
    const float* bp = (const float*)d_in[5];
    float* out = (float*)d_out;

    _Float16* Xf  = (_Float16*)d_ws;                 // 8192x1024
    _Float16* Wqt = Xf  + (size_t)8388608;           // 16x64x1024  } contiguous =
    _Float16* Wkt = Wqt + (size_t)1048576;           //             } Wcat[3072][1024]
    _Float16* Wvt = Wkt + (size_t)1048576;           //             }
    _Float16* Wpt = Wvt + (size_t)1048576;           // 1024x1024 (transposed)
    _Float16* Qf  = Wpt + (size_t)1048576;           // 64x2048x64  (pre-scaled)
    _Float16* Kf  = Qf  + (size_t)8388608;
    _Float16* Vt  = Kf  + (size_t)8388608;           // 64x64x2048 (transposed)
    _Float16* att = Vt  + (size_t)8388608;           // 4x2048x1024

    convx_kernel<<<4096, 256, 0, stream>>>(x, Xf);
    convw_qkv_kernel<<<dim3(8, 16, 3), 256, 0, stream>>>(Wq, Wk, Wv, Wqt, Wkt, Wvt);
    convw_p_kernel<<<dim3(16, 16), 256, 0, stream>>>(Wp, Wpt);
    qkv4_kernel<<<dim3(64, 16), 256, 0, stream>>>(Xf, Wqt, Qf, Kf, Vt);
    flash_kernel<<<dim3(64, 8), 256, 0, stream>>>(Qf, Kf, Vt, att);
    proj2_kernel<<<dim3(64, 8), 256, 0, stream>>>(att, Wpt, bp, out);
}

// Round 19
// 172.152 us; speedup vs baseline: 1.2956x; 1.0722x over previous
//
#include <hip/hip_runtime.h>

#define B_ 4
#define T_ 2048
#define C_ 1024
#define H_ 16
#define D_ 64

typedef _Float16 f16x8 __attribute__((ext_vector_type(8)));
typedef __fp16 fp16x2 __attribute__((ext_vector_type(2)));
typedef float f32x4 __attribute__((ext_vector_type(4)));
typedef unsigned short u16x8 __attribute__((ext_vector_type(8)));

#define MFMA16 __builtin_amdgcn_mfma_f32_16x16x32_f16
#define SCALE2 11.541560327111707f   /* 8 * log2(e), pre-folded into Q */

__device__ __forceinline__ unsigned pk2(float a, float b) {
    fp16x2 p = __builtin_amdgcn_cvt_pkrtz(a, b);
    return __builtin_bit_cast(unsigned, p);
}

__device__ __forceinline__ void gl_lds16(const _Float16* g, unsigned short* lds) {
    __builtin_amdgcn_global_load_lds(
        (const __attribute__((address_space(1))) unsigned int*)g,
        (__attribute__((address_space(3))) unsigned int*)lds, 16, 0, 0);
}

// ---------------------------------------------------------------------------
// convx: x fp32 -> Xf fp16.  grid 4096, block 256.
// ---------------------------------------------------------------------------
__global__ __launch_bounds__(256) void convx_kernel(const float* __restrict__ x,
                                                    _Float16* __restrict__ Xf) {
    size_t i = ((size_t)blockIdx.x * 256 + threadIdx.x) * 8;
    f32x4 a = *reinterpret_cast<const f32x4*>(x + i);
    f32x4 b = *reinterpret_cast<const f32x4*>(x + i + 4);
    f16x8 o;
    o[0] = (_Float16)a[0]; o[1] = (_Float16)a[1]; o[2] = (_Float16)a[2]; o[3] = (_Float16)a[3];
    o[4] = (_Float16)b[0]; o[5] = (_Float16)b[1]; o[6] = (_Float16)b[2]; o[7] = (_Float16)b[3];
    *reinterpret_cast<f16x8*>(Xf + i) = o;
}

// ---------------------------------------------------------------------------
// convw_qkv: W[h][c][d] fp32 -> Wt[h][d][c] fp16 (transposed).  grid(8,16,3).
// ---------------------------------------------------------------------------
__global__ __launch_bounds__(256) void convw_qkv_kernel(
    const float* __restrict__ Wq, const float* __restrict__ Wk, const float* __restrict__ Wv,
    _Float16* __restrict__ Wqt, _Float16* __restrict__ Wkt, _Float16* __restrict__ Wvt)
{
    __shared__ unsigned short Wl[128][72];
    const int ct = blockIdx.x, h = blockIdx.y, m = blockIdx.z;
    const float* src = (m == 0 ? Wq : (m == 1 ? Wk : Wv)) + ((size_t)h * C_ + ct * 128) * D_;
    _Float16* dst = (m == 0 ? Wqt : (m == 1 ? Wkt : Wvt));
    const int tid = threadIdx.x;
    {
        int r = tid >> 1, half = tid & 1;
        #pragma unroll
        for (int i = 0; i < 8; i++) {
            f32x4 v = *reinterpret_cast<const f32x4*>(src + (size_t)r * D_ + half * 32 + i * 4);
            #pragma unroll
            for (int j = 0; j < 4; j++)
                Wl[r][half * 32 + i * 4 + j] = __builtin_bit_cast(unsigned short, (_Float16)v[j]);
        }
    }
    __syncthreads();
    {
        int d = tid >> 2, seg = tid & 3;
        #pragma unroll
        for (int i = 0; i < 4; i++) {
            u16x8 o;
            #pragma unroll
            for (int j = 0; j < 8; j++) o[j] = Wl[seg * 32 + i * 8 + j][d];
            *reinterpret_cast<u16x8*>((unsigned short*)dst + ((size_t)h * D_ + d) * C_ + ct * 128 + seg * 32 + i * 8) = o;
        }
    }
}

// ---------------------------------------------------------------------------
// convw_p: Wp[k][j] fp32 -> Wpt[j][k] fp16.  grid(16,16).
// ---------------------------------------------------------------------------
__global__ __launch_bounds__(256) void convw_p_kernel(const float* __restrict__ Wp,
                                                      _Float16* __restrict__ Wpt)
{
    __shared__ unsigned short Pl[64][72];
    const int jt = blockIdx.x, kt = blockIdx.y;
    const int tid = threadIdx.x;
    {
        int r = tid >> 2, seg = tid & 3;
        #pragma unroll
        for (int i = 0; i < 4; i++) {
            f32x4 v = *reinterpret_cast<const f32x4*>(Wp + (size_t)(kt * 64 + r) * C_ + jt * 64 + seg * 16 + i * 4);
            #pragma unroll
            for (int j = 0; j < 4; j++)
                Pl[r][seg * 16 + i * 4 + j] = __builtin_bit_cast(unsigned short, (_Float16)v[j]);
        }
    }
    __syncthreads();
    {
        int jj = tid >> 2, kseg = tid & 3;
        #pragma unroll
        for (int i = 0; i < 2; i++) {
            u16x8 o;
            #pragma unroll
            for (int j = 0; j < 8; j++) o[j] = Pl[kseg * 16 + i * 8 + j][jj];
            *reinterpret_cast<u16x8*>((unsigned short*)Wpt + (size_t)(jt * 64 + jj) * C_ + kt * 64 + kseg * 16 + i * 8) = o;
        }
    }
}

// ---------------------------------------------------------------------------
// qkv6: qkv4 + T2 XOR-swizzle on As/Bs (pre-swizzled gl_lds16 source +
// swizzled ds_read, flash's proven involution).  128x192 tile, BK=64,
// 4 waves (2x2, per-wave 64x96).  grid(64, 16) = 4 blocks/CU x 1 gen.
// ---------------------------------------------------------------------------
__global__ __launch_bounds__(256) void qkv6_kernel(
    const _Float16* __restrict__ Xf, const _Float16* __restrict__ Wcat,
    _Float16* __restrict__ Qf, _Float16* __restrict__ Kf, _Float16* __restrict__ Vt)
{
    __shared__ unsigned short As[128 * 64];
    __shared__ unsigned short Bs[192 * 64];
    const int rt = blockIdx.x, ct = blockIdx.y;
    const int row0 = rt * 128, n0 = ct * 192;
    const int tid = threadIdx.x, wid = tid >> 6, lane = tid & 63;
    const int l15 = lane & 15, g = lane >> 4;
    const int wr = wid >> 1, wc = wid & 1;
    const int lrow = lane >> 3;                       // 0..7 within 8-row chunk
    const int lcols = ((lane & 7) ^ lrow) * 8;        // pre-swizzled source unit

    f32x4 acc[4][6];
    #pragma unroll
    for (int mi = 0; mi < 4; mi++)
        #pragma unroll
        for (int ni = 0; ni < 6; ni++) { f32x4 z = {0.f,0.f,0.f,0.f}; acc[mi][ni] = z; }

    for (int k0 = 0; k0 < C_; k0 += 64) {
        __syncthreads();
        #pragma unroll
        for (int i = 0; i < 4; i++) {
            int c = wid * 4 + i;
            gl_lds16(Xf + (size_t)(row0 + c * 8 + lrow) * C_ + k0 + lcols, &As[c * 512]);
        }
        #pragma unroll
        for (int i = 0; i < 6; i++) {
            int c = wid * 6 + i;
            gl_lds16(Wcat + (size_t)(n0 + c * 8 + lrow) * C_ + k0 + lcols, &Bs[c * 512]);
        }
        __syncthreads();
        #pragma unroll
        for (int kk = 0; kk < 2; kk++) {
            f16x8 af[4];
            #pragma unroll
            for (int mi = 0; mi < 4; mi++) {
                int row = wr * 64 + mi * 16 + l15;
                af[mi] = *reinterpret_cast<const f16x8*>(
                    &As[row * 64 + (((kk * 4 + g) ^ (row & 7)) * 8)]);
            }
            #pragma unroll
            for (int ni = 0; ni < 6; ni++) {
                int row = wc * 96 + ni * 16 + l15;
                f16x8 bf = *reinterpret_cast<const f16x8*>(
                    &Bs[row * 64 + (((kk * 4 + g) ^ (row & 7)) * 8)]);
                #pragma unroll
                for (int mi = 0; mi < 4; mi++)
                    acc[mi][ni] = MFMA16(af[mi], bf, acc[mi][ni], 0, 0, 0);
            }
        }
    }

    const int b = row0 >> 11;
    const int t0b = (row0 & (T_ - 1)) + wr * 64;
    #pragma unroll
    for (int ni = 0; ni < 6; ni++) {
        const int n = n0 + wc * 96 + ni * 16;
        const int region = n >> 10;             // 0=Q, 1=K, 2=V (wave-uniform)
        const int h = (n >> 6) & 15;
        const int d0 = n & 63;
        if (region < 2) {
            _Float16* dst = region ? Kf : Qf;
            const float osc = region ? 1.0f : SCALE2;
            const size_t hb = ((size_t)(b * H_ + h)) * T_ * D_;
            #pragma unroll
            for (int mi = 0; mi < 4; mi++)
                #pragma unroll
                for (int r = 0; r < 4; r++) {
                    int t = t0b + mi * 16 + g * 4 + r;
                    dst[hb + (size_t)t * D_ + d0 + l15] = (_Float16)(acc[mi][ni][r] * osc);
                }
        } else {
            const size_t vbase = ((size_t)(b * H_ + h)) * D_ * T_;
            const int d = d0 + l15;
            #pragma unroll
            for (int mi = 0; mi < 4; mi++) {
                int t = t0b + mi * 16 + g * 4;
                uint2 w;
                w.x = pk2(acc[mi][ni][0], acc[mi][ni][1]);
                w.y = pk2(acc[mi][ni][2], acc[mi][ni][3]);
                *reinterpret_cast<uint2*>((unsigned short*)Vt + vbase + (size_t)d * T_ + t) = w;
            }
        }
    }
}

// ---------------------------------------------------------------------------
// flash: causal attention, 128-kv super-tiles (dbuf K+V), two 64-kv sub-tiles,
// 1 barrier per super-tile.  grid(64 bh, 8 p) paired-uniform.
// Mask hoisted to last-sub-tile-only; row-sum on the matrix pipe.
// ---------------------------------------------------------------------------
__global__ __launch_bounds__(256) void flash_kernel(
    const _Float16* __restrict__ Qf, const _Float16* __restrict__ Kf,
    const _Float16* __restrict__ Vt, _Float16* __restrict__ att)
{
    __shared__ __align__(16) unsigned short Ks[2][128 * 64];  // [buf][kv][d]  128B rows
    __shared__ __align__(16) unsigned short Vs[2][64 * 128];  // [buf][d][kv]  256B rows
    __shared__ __align__(16) unsigned short Ps[4][32 * 32];   // per-wave P kv-half
    const int bh = blockIdx.x;
    const int p = (int)blockIdx.y;           // 0..7
    const int bb = bh >> 4, h = bh & 15;
    const int tid = threadIdx.x, wid = tid >> 6, lane = tid & 63;
    const int l15 = lane & 15, g = lane >> 4;

    const _Float16* Qb = Qf + (size_t)bh * T_ * D_;
    const _Float16* Kb = Kf + (size_t)bh * T_ * D_;
    const _Float16* Vb = Vt + (size_t)bh * D_ * T_;

    const int srow = lane >> 3;                  // K staging
    const int sunit = (lane & 7) ^ srow;
    const int r0k = wid * 32;
    const int vsrow = lane >> 4;                 // V staging (256B rows)
    const int r0v = wid * 16;

    char* const pbase = (char*)&Ps[wid][0];

    f16x8 ones;
    #pragma unroll
    for (int j = 0; j < 8; j++) ones[j] = (_Float16)1.0f;

    for (int pass = 0; pass < 2; pass++) {
        const int qt = pass ? p : (15 - p);
        const int q0 = qt * 128;
        const int qw = q0 + wid * 32;

        f16x8 qf[2][2];
        #pragma unroll
        for (int mt = 0; mt < 2; mt++)
            #pragma unroll
            for (int kk = 0; kk < 2; kk++)
                qf[mt][kk] = *reinterpret_cast<const f16x8*>(Qb + (size_t)(qw + mt * 16 + l15) * D_ + kk * 32 + g * 8);

        f32x4 accO[4][2];
        #pragma unroll
        for (int nt = 0; nt < 4; nt++)
            #pragma unroll
            for (int mt = 0; mt < 2; mt++) { f32x4 z = {0.f,0.f,0.f,0.f}; accO[nt][mt] = z; }
        float m[2] = { -1e30f, -1e30f };
        float l[2] = { 0.f, 0.f };

        const int nSup = qt + 1;                 // super-tiles (wave-uniform)
        const int mySub = (qw + 95) >> 6;        // 64-kv sub-tiles this wave computes

        // prologue: stage super-tile 0 into buf 0
        #pragma unroll
        for (int i = 0; i < 4; i++) {
            int krow = r0k + i * 8 + srow;
            gl_lds16(Kb + (size_t)krow * D_ + sunit * 8, &Ks[0][(r0k + i * 8) * 64]);
            int vrow = r0v + i * 4 + vsrow;
            int vsunit = (lane & 15) ^ (vrow & 7);
            gl_lds16(Vb + (size_t)vrow * T_ + vsunit * 8, &Vs[0][(r0v + i * 4) * 128]);
        }
        __syncthreads();

#define SUB_TILE(SP, SH, MASKED)                                                    \
    {                                                                               \
        const int kv0 = ((SP) * 2 + (SH)) * 64;                                     \
        f32x4 s[4][2];                                                              \
        _Pragma("unroll")                                                           \
        for (int st = 0; st < 4; st++)                                              \
            _Pragma("unroll")                                                       \
            for (int mt = 0; mt < 2; mt++) { f32x4 z = {0.f,0.f,0.f,0.f}; s[st][mt] = z; } \
        _Pragma("unroll")                                                           \
        for (int kk = 0; kk < 2; kk++) {                                            \
            f16x8 kfr[4];                                                           \
            _Pragma("unroll")                                                       \
            for (int st = 0; st < 4; st++) {                                        \
                int row = (SH) * 64 + st * 16 + l15;                                \
                kfr[st] = *reinterpret_cast<const f16x8*>(                          \
                    kb128 + row * 128 + (((kk * 4 + g) ^ (row & 7)) * 16));         \
            }                                                                       \
            _Pragma("unroll")                                                       \
            for (int st = 0; st < 4; st++)                                          \
                _Pragma("unroll")                                                   \
                for (int mt = 0; mt < 2; mt++)                                      \
                    s[st][mt] = MFMA16(kfr[st], qf[mt][kk], s[st][mt], 0, 0, 0);    \
        }                                                                           \
        unsigned pw[2][4][2];                                                       \
        _Pragma("unroll")                                                           \
        for (int mt = 0; mt < 2; mt++) {                                            \
            if (MASKED) {                                                           \
                const int qrow = qw + mt * 16 + l15;                                \
                _Pragma("unroll")                                                   \
                for (int st = 0; st < 4; st++)                                      \
                    _Pragma("unroll")                                               \
                    for (int rr = 0; rr < 4; rr++) {                                \
                        int kv = kv0 + st * 16 + g * 4 + rr;                        \
                        s[st][mt][rr] = (kv <= qrow) ? s[st][mt][rr] : -1e30f;      \
                    }                                                               \
            }                                                                       \
            float vmax = -1e30f;                                                    \
            _Pragma("unroll")                                                       \
            for (int st = 0; st < 4; st++)                                          \
                _Pragma("unroll")                                                   \
                for (int rr = 0; rr < 4; rr++)                                      \
                    vmax = fmaxf(vmax, s[st][mt][rr]);                              \
            vmax = fmaxf(vmax, __shfl_xor(vmax, 16, 64));                           \
            vmax = fmaxf(vmax, __shfl_xor(vmax, 32, 64));                           \
            if (__any(vmax > m[mt])) {                                              \
                float mnew = fmaxf(m[mt], vmax);                                    \
                float alpha = __builtin_amdgcn_exp2f(m[mt] - mnew);                 \
                m[mt] = mnew;                                                       \
                l[mt] *= alpha;                                                     \
                _Pragma("unroll")                                                   \
                for (int nt = 0; nt < 4; nt++) accO[nt][mt] *= alpha;               \
            }                                                                       \
            _Pragma("unroll")                                                       \
            for (int st = 0; st < 4; st++) {                                        \
                float p0 = __builtin_amdgcn_exp2f(s[st][mt][0] - m[mt]);            \
                float p1 = __builtin_amdgcn_exp2f(s[st][mt][1] - m[mt]);            \
                float p2 = __builtin_amdgcn_exp2f(s[st][mt][2] - m[mt]);            \
                float p3 = __builtin_amdgcn_exp2f(s[st][mt][3] - m[mt]);            \
                pw[mt][st][0] = pk2(p0, p1);                                        \
                pw[mt][st][1] = pk2(p2, p3);                                        \
            }                                                                       \
        }                                                                           \
        f32x4 rsacc[2];                                                             \
        { f32x4 z = {0.f,0.f,0.f,0.f}; rsacc[0] = z; rsacc[1] = z; }                \
        _Pragma("unroll")                                                           \
        for (int ph = 0; ph < 2; ph++) {                                            \
            _Pragma("unroll")                                                       \
            for (int mt = 0; mt < 2; mt++) {                                        \
                const int r = mt * 16 + l15;                                        \
                const int swz = ((r >> 1) & 3) << 4;                                \
                char* prow = pbase + r * 64;                                        \
                _Pragma("unroll")                                                   \
                for (int stl = 0; stl < 2; stl++) {                                 \
                    uint2 w;                                                        \
                    w.x = pw[mt][ph * 2 + stl][0];                                  \
                    w.y = pw[mt][ph * 2 + stl][1];                                  \
                    *reinterpret_cast<uint2*>(prow + ((stl * 32 + g * 8) ^ swz)) = w; \
                }                                                                   \
            }                                                                       \
            f16x8 pb[2];                                                            \
            _Pragma("unroll")                                                       \
            for (int mt = 0; mt < 2; mt++) {                                        \
                const int r = mt * 16 + l15;                                        \
                const int swz = ((r >> 1) & 3) << 4;                                \
                pb[mt] = *reinterpret_cast<const f16x8*>(pbase + r * 64 + ((g * 16) ^ swz)); \
            }                                                                       \
            rsacc[0] = MFMA16(ones, pb[0], rsacc[0], 0, 0, 0);                      \
            rsacc[1] = MFMA16(ones, pb[1], rsacc[1], 0, 0, 0);                      \
            _Pragma("unroll")                                                       \
            for (int nt = 0; nt < 4; nt++) {                                        \
                int row = nt * 16 + l15;                                            \
                int unit = ((SH) * 8 + ph * 4 + g) ^ (row & 7);                     \
                f16x8 vf = *reinterpret_cast<const f16x8*>(                         \
                    vb128 + row * 256 + unit * 16);                                 \
                _Pragma("unroll")                                                   \
                for (int mt = 0; mt < 2; mt++)                                      \
                    accO[nt][mt] = MFMA16(vf, pb[mt], accO[nt][mt], 0, 0, 0);       \
            }                                                                       \
        }                                                                           \
        l[0] += rsacc[0][0];                                                        \
        l[1] += rsacc[1][0];                                                        \
    }

#define SUPER_BODY(SP, BUF)                                                         \
    {                                                                               \
        if ((SP) + 1 < nSup) {                                                      \
            const int kvn = ((SP) + 1) * 128;                                       \
            _Pragma("unroll")                                                       \
            for (int i = 0; i < 4; i++) {                                           \
                int krow = r0k + i * 8 + srow;                                      \
                gl_lds16(Kb + (size_t)(kvn + krow) * D_ + sunit * 8,                \
                         &Ks[(BUF) ^ 1][(r0k + i * 8) * 64]);                       \
                int vrow = r0v + i * 4 + vsrow;                                     \
                int vsunit = (lane & 15) ^ (vrow & 7);                              \
                gl_lds16(Vb + (size_t)vrow * T_ + kvn + vsunit * 8,                 \
                         &Vs[(BUF) ^ 1][(r0v + i * 4) * 128]);                      \
            }                                                                       \
        }                                                                           \
        const char* kb128 = (const char*)&Ks[BUF][0];                               \
        const char* vb128 = (const char*)&Vs[BUF][0];                               \
        if ((SP) * 2 + 1 < mySub)      { SUB_TILE(SP, 0, 0) }                       \
        else if ((SP) * 2 < mySub)     { SUB_TILE(SP, 0, 1) }                       \
        if ((SP) * 2 + 2 < mySub)      { SUB_TILE(SP, 1, 0) }                       \
        else if ((SP) * 2 + 1 < mySub) { SUB_TILE(SP, 1, 1) }                       \
        __syncthreads();                                                            \
    }

        for (int sp = 0; sp < nSup; sp += 2) {
            SUPER_BODY(sp, 0)
            if (sp + 1 < nSup) {
                SUPER_BODY(sp + 1, 1)
            }
        }
#undef SUPER_BODY
#undef SUB_TILE

        // epilogue: normalize, write att [b][t][h*64+d] fp16
        #pragma unroll
        for (int mt = 0; mt < 2; mt++) {
            float inv = 1.0f / l[mt];
            int t = qw + mt * 16 + l15;
            #pragma unroll
            for (int nt = 0; nt < 4; nt++) {
                f32x4 o = accO[nt][mt] * inv;
                uint2 w;
                w.x = pk2(o[0], o[1]);
                w.y = pk2(o[2], o[3]);
                size_t off = ((size_t)(bb * T_ + t)) * (H_ * D_) + h * D_ + nt * 16 + g * 4;
                *reinterpret_cast<uint2*>((unsigned short*)att + off) = w;
            }
        }
    }
}

// ---------------------------------------------------------------------------
// proj3: proj2 + T2 XOR-swizzle on As/Bs (same involution as qkv6).
// grid(64, 8), block 256 (4 waves, 2x2).  128x128 tile, BK=64.
// ---------------------------------------------------------------------------
__global__ __launch_bounds__(256) void proj3_kernel(
    const _Float16* __restrict__ att, const _Float16* __restrict__ Wpt,
    const float* __restrict__ bp, float* __restrict__ out)
{
    __shared__ unsigned short As[128 * 64];
    __shared__ unsigned short Bs[128 * 64];
    const int rt = blockIdx.x, ct = blockIdx.y;
    const int row0 = rt * 128, n0 = ct * 128;
    const int tid = threadIdx.x, wid = tid >> 6, lane = tid & 63;
    const int l15 = lane & 15, g = lane >> 4;
    const int wr = wid >> 1, wc = wid & 1;
    const int lrow = lane >> 3;
    const int lcols = ((lane & 7) ^ lrow) * 8;

    f32x4 acc[4][4];
    #pragma unroll
    for (int mi = 0; mi < 4; mi++)
        #pragma unroll
        for (int ni = 0; ni < 4; ni++) { f32x4 z = {0.f,0.f,0.f,0.f}; acc[mi][ni] = z; }

    for (int k0 = 0; k0 < C_; k0 += 64) {
        __syncthreads();
        #pragma unroll
        for (int i = 0; i < 4; i++) {
            int c = wid * 4 + i;
            gl_lds16(att + (size_t)(row0 + c * 8 + lrow) * C_ + k0 + lcols, &As[c * 512]);
            gl_lds16(Wpt + (size_t)(n0   + c * 8 + lrow) * C_ + k0 + lcols, &Bs[c * 512]);
        }
        __syncthreads();
        #pragma unroll
        for (int kk = 0; kk < 2; kk++) {
            f16x8 af[4], bf[4];
            #pragma unroll
            for (int mi = 0; mi < 4; mi++) {
                int row = wr * 64 + mi * 16 + l15;
                af[mi] = *reinterpret_cast<const f16x8*>(
                    &As[row * 64 + (((kk * 4 + g) ^ (row & 7)) * 8)]);
            }
            #pragma unroll
            for (int ni = 0; ni < 4; ni++) {
                int row = wc * 64 + ni * 16 + l15;
                bf[ni] = *reinterpret_cast<const f16x8*>(
                    &Bs[row * 64 + (((kk * 4 + g) ^ (row & 7)) * 8)]);
            }
            #pragma unroll
            for (int mi = 0; mi < 4; mi++)
                #pragma unroll
                for (int ni = 0; ni < 4; ni++)
                    acc[mi][ni] = MFMA16(af[mi], bf[ni], acc[mi][ni], 0, 0, 0);
        }
    }

    #pragma unroll
    for (int mi = 0; mi < 4; mi++)
        #pragma unroll
        for (int ni = 0; ni < 4; ni++) {
            int col = n0 + wc * 64 + ni * 16 + l15;
            float bias = bp[col];
            #pragma unroll
            for (int r = 0; r < 4; r++) {
                int row = row0 + wr * 64 + mi * 16 + g * 4 + r;
                out[(size_t)row * C_ + col] = acc[mi][ni][r] + bias;
            }
        }
}

// ---------------------------------------------------------------------------
extern "C" void kernel_launch(void* const* d_in, const int* in_sizes, int n_in,
                              void* d_out, int out_size, void* d_ws, size_t ws_size,
                              hipStream_t stream) {
    const float* x  = (const float*)d_in[0];
    const float* Wq = (const float*)d_in[1];
    const float* Wk = (const float*)d_in[2];
    const float* Wv = (const float*)d_in[3];
    const float* Wp = (const float*)d_in[4];
    const float* bp = (const float*)d_in[5];
    float* out = (float*)d_out;

    _Float16* Xf  = (_Float16*)d_ws;                 // 8192x1024
    _Float16* Wqt = Xf  + (size_t)8388608;           // 16x64x1024  } contiguous =
    _Float16* Wkt = Wqt + (size_t)1048576;           //             } Wcat[3072][1024]
    _Float16* Wvt = Wkt + (size_t)1048576;           //             }
    _Float16* Wpt = Wvt + (size_t)1048576;           // 1024x1024 (transposed)
    _Float16* Qf  = Wpt + (size_t)1048576;           // 64x2048x64  (pre-scaled)
    _Float16* Kf  = Qf  + (size_t)8388608;
    _Float16* Vt  = Kf  + (size_t)8388608;           // 64x64x2048 (transposed)
    _Float16* att = Vt  + (size_t)8388608;           // 4x2048x1024

    convx_kernel<<<4096, 256, 0, stream>>>(x, Xf);
    convw_qkv_kernel<<<dim3(8, 16, 3), 256, 0, stream>>>(Wq, Wk, Wv, Wqt, Wkt, Wvt);
    convw_p_kernel<<<dim3(16, 16), 256, 0, stream>>>(Wp, Wpt);
    qkv6_kernel<<<dim3(64, 16), 256, 0, stream>>>(Xf, Wqt, Qf, Kf, Vt);
    flash_kernel<<<dim3(64, 8), 256, 0, stream>>>(Qf, Kf, Vt, att);
    proj3_kernel<<<dim3(64, 8), 256, 0, stream>>>(att, Wpt, bp, out);
}